// Round 19
// baseline (221.913 us; speedup 1.0000x reference)
//
#include <hip/hip_runtime.h>
#include <hip/hip_bf16.h>

#define NQ   900
#define BSZ  8
#define DM   256
#define NH   8
#define DHD  32
#define DFF_ 1024
#define LVTOT 13294
#define NTOK (NQ*BSZ)    // 7200
#define MVAL (LVTOT*BSZ) // 106352

typedef __attribute__((ext_vector_type(8))) short bf16x8;
typedef __attribute__((ext_vector_type(4))) short bf16x4;
typedef __attribute__((ext_vector_type(4))) float f32x4;
typedef unsigned int u32;

__device__ __forceinline__ unsigned short f2bf(float x) {
  union { __hip_bfloat16 h; unsigned short u; } cv;
  cv.h = __float2bfloat16(x);
  return cv.u;
}
__device__ __forceinline__ float bf2f(unsigned short u) {
  union { __hip_bfloat16 h; unsigned short u; } cv;
  cv.u = u;
  return __bfloat162float(cv.h);
}

__device__ __forceinline__ void gl_lds16(const void* gsrc, void* ldst) {
  __builtin_amdgcn_global_load_lds(
      (const __attribute__((address_space(1))) u32*)gsrc,
      (__attribute__((address_space(3))) u32*)ldst, 16, 0, 0);
}

// ---------------- fused prep: weights-cast ++ addcast(q=tgt+pos) ++ bias-concat ----------------
__global__ __launch_bounds__(256) void prep_kernel(
    const float* p0, const float* p1, const float* p2, const float* p3,
    const float* p4, const float* p5, const float* p6, const float* p7,
    unsigned short* wdst,
    const float* a, const float* b, unsigned short* qdst,
    const float* boff, const float* battn, float* bcat) {
  int bid = blockIdx.x, tid = threadIdx.x;
  if (bid < 496) {
    long i8 = ((long)bid * 256 + tid) * 8;
    const float* src; long off;
    if      (i8 < 196608) { src = p0; off = i8; }
    else if (i8 < 262144) { src = p1; off = i8 - 196608; }
    else if (i8 < 327680) { src = p2; off = i8 - 262144; }
    else if (i8 < 393216) { src = p3; off = i8 - 327680; }
    else if (i8 < 425984) { src = p4; off = i8 - 393216; }
    else if (i8 < 491520) { src = p5; off = i8 - 425984; }
    else if (i8 < 753664) { src = p6; off = i8 - 491520; }
    else                  { src = p7; off = i8 - 753664; }
    float4 x = *(const float4*)(src + off);
    float4 y = *(const float4*)(src + off + 4);
    bf16x8 v;
    v[0] = (short)f2bf(x.x); v[1] = (short)f2bf(x.y);
    v[2] = (short)f2bf(x.z); v[3] = (short)f2bf(x.w);
    v[4] = (short)f2bf(y.x); v[5] = (short)f2bf(y.y);
    v[6] = (short)f2bf(y.z); v[7] = (short)f2bf(y.w);
    *(bf16x8*)(wdst + i8) = v;
  } else if (bid < 496 + 900) {
    int i = (bid - 496) * 256 + tid;
    float4 a0 = ((const float4*)a)[i * 2], a1 = ((const float4*)a)[i * 2 + 1];
    float4 b0 = ((const float4*)b)[i * 2], b1 = ((const float4*)b)[i * 2 + 1];
    bf16x8 v;
    v[0] = (short)f2bf(a0.x + b0.x); v[1] = (short)f2bf(a0.y + b0.y);
    v[2] = (short)f2bf(a0.z + b0.z); v[3] = (short)f2bf(a0.w + b0.w);
    v[4] = (short)f2bf(a1.x + b1.x); v[5] = (short)f2bf(a1.y + b1.y);
    v[6] = (short)f2bf(a1.z + b1.z); v[7] = (short)f2bf(a1.w + b1.w);
    *(bf16x8*)(qdst + (long)i * 8) = v;
  } else {
    int i = (bid - 1396) * 256 + tid;
    if (i < 256) bcat[i] = boff[i];
    else if (i < 384) bcat[i] = battn[i - 256];
  }
}

// ---------------- batched GEMM descriptor (ops 1,2 used for qk + v-part) ----------------
struct B3 {
  const void* A[3];
  const unsigned short* W[3];
  const float* bias[3];
  void* C[3];
  int M[3], ldc[3], af32[3], blk0[3], nx[3];
};

__global__ __launch_bounds__(256, 4) void gemm_batch3_kernel(B3 ops) {
  constexpr int K = 256, NSTEP = 4;
  __shared__ alignas(16) unsigned char As[32768];
  __shared__ alignas(16) unsigned char Bs[16384];
  int bid = blockIdx.x;
  int oi = (bid >= ops.blk0[2]) ? 2 : (bid >= ops.blk0[1] ? 1 : 0);
  int rel = bid - ops.blk0[oi];
  int nx = ops.nx[oi];
  int bx = rel % nx, by = rel / nx;
  const void* Araw = ops.A[oi];
  const unsigned short* W = ops.W[oi];
  const float* bias = ops.bias[oi];
  void* C = ops.C[oi];
  int M = ops.M[oi], ldc = ops.ldc[oi], AF32 = ops.af32[oi];

  int tid = threadIdx.x;
  int l = tid & 63, w = tid >> 6;
  int lr = l & 15, lg = l >> 4;
  int wr = w >> 1, wc = w & 1;
  int n0 = bx * 128, m0 = by * 128;
  int phase = by & (NSTEP - 1);

  f32x4 acc[4][4];
#pragma unroll
  for (int m = 0; m < 4; m++)
#pragma unroll
    for (int n = 0; n < 4; n++) acc[m][n] = (f32x4){0.f, 0.f, 0.f, 0.f};

  for (int tt = 0; tt < NSTEP; tt++) {
    int t = tt + phase; if (t >= NSTEP) t -= NSTEP;
    int k0 = t * 64;
    __syncthreads();
#pragma unroll
    for (int i4 = 0; i4 < 4; i4++) {
      int i = i4 * 4 + w;
      int row = i * 8 + (l >> 3);
      int sc = (l & 7) ^ (row & 7);
      gl_lds16(W + (long)(n0 + row) * K + k0 + sc * 8, Bs + i * 1024 + l * 16);
    }
    if (AF32) {
      const float* Af = (const float*)Araw;
#pragma unroll
      for (int i4 = 0; i4 < 8; i4++) {
        int i = i4 * 4 + w;
        int row = i * 4 + (l >> 4);
        int g = m0 + row; if (g >= M) g = M - 1;
        int sc = (l & 15) ^ (row & 15);
        gl_lds16(Af + (long)g * K + k0 + sc * 4, As + i * 1024 + l * 16);
      }
    } else {
      const unsigned short* A = (const unsigned short*)Araw;
#pragma unroll
      for (int i4 = 0; i4 < 4; i4++) {
        int i = i4 * 4 + w;
        int row = i * 8 + (l >> 3);
        int g = m0 + row; if (g >= M) g = M - 1;
        int sc = (l & 7) ^ (row & 7);
        gl_lds16(A + (long)g * K + k0 + sc * 8, As + i * 1024 + l * 16);
      }
    }
    __syncthreads();
#pragma unroll
    for (int sk = 0; sk < 2; sk++) {
      bf16x8 af[4], bfr[4];
      if (AF32) {
#pragma unroll
        for (int m = 0; m < 4; m++) {
          int row = wr * 64 + m * 16 + lr;
          int ca = (sk * 8 + lg * 2) ^ (row & 15);
          int cb = (sk * 8 + lg * 2 + 1) ^ (row & 15);
          f32x4 fa = *(const f32x4*)(As + row * 256 + ca * 16);
          f32x4 fb = *(const f32x4*)(As + row * 256 + cb * 16);
          bf16x8 v;
          v[0] = (short)f2bf(fa[0]); v[1] = (short)f2bf(fa[1]);
          v[2] = (short)f2bf(fa[2]); v[3] = (short)f2bf(fa[3]);
          v[4] = (short)f2bf(fb[0]); v[5] = (short)f2bf(fb[1]);
          v[6] = (short)f2bf(fb[2]); v[7] = (short)f2bf(fb[3]);
          af[m] = v;
        }
      } else {
#pragma unroll
        for (int m = 0; m < 4; m++) {
          int row = wr * 64 + m * 16 + lr;
          int c = (sk * 4 + lg) ^ (row & 7);
          af[m] = *(const bf16x8*)(As + row * 128 + c * 16);
        }
      }
#pragma unroll
      for (int n = 0; n < 4; n++) {
        int row = wc * 64 + n * 16 + lr;
        int c = (sk * 4 + lg) ^ (row & 7);
        bfr[n] = *(const bf16x8*)(Bs + row * 128 + c * 16);
      }
#pragma unroll
      for (int m = 0; m < 4; m++)
#pragma unroll
        for (int n = 0; n < 4; n++)
          acc[m][n] = __builtin_amdgcn_mfma_f32_16x16x32_bf16(af[m], bfr[n], acc[m][n], 0, 0, 0);
    }
  }

  float bv[4];
#pragma unroll
  for (int ni = 0; ni < 4; ni++) bv[ni] = bias[n0 + wc * 64 + ni * 16 + lr];
#pragma unroll
  for (int mi = 0; mi < 4; mi++) {
#pragma unroll
    for (int r = 0; r < 4; r++) {
      int row = m0 + wr * 64 + mi * 16 + lg * 4 + r;
      if (row < M) {
#pragma unroll
        for (int ni = 0; ni < 4; ni++) {
          int col = n0 + wc * 64 + ni * 16 + lr;
          ((unsigned short*)C)[(long)row * ldc + col] = f2bf(acc[mi][ni][r] + bv[ni]);
        }
      }
    }
  }
}

// ======== HETEROGENEOUS fused launch: value-projection GEMM (blocks 0..NVB-1) ========
// ======== in parallel with XCD-clustered flash attention (blocks NVB..NVB+959) ========
// Value: [106352,256] = memory(f32) @ Wval^T, bf16 out (nx=2, K-phase rotation).
// Attn: identical math to R18's attn_mfma_kernel, bid' = bid - NVB.
// Shared memory is a 48KB union (attn uses 14KB of it).
#define NVB 1662
__global__ __launch_bounds__(256, 4) void value_attn_kernel(
    const float* __restrict__ memory, const unsigned short* __restrict__ Wv,
    const float* __restrict__ bval, unsigned short* __restrict__ Cv,
    const unsigned short* __restrict__ qkv, unsigned short* __restrict__ out) {
  __shared__ alignas(16) unsigned char smem[49152];
  int tid = threadIdx.x;
  int l = tid & 63, w = tid >> 6;
  int lr = l & 15, lg = l >> 4;

  if (blockIdx.x < NVB) {
    // ---------------- value-projection GEMM path ----------------
    constexpr int K = 256, NSTEP = 4;
    unsigned char* As = smem;            // 32768
    unsigned char* Bs = smem + 32768;    // 16384
    int wr = w >> 1, wc = w & 1;
    int bx = blockIdx.x & 1, by = blockIdx.x >> 1;
    int n0 = bx * 128, m0 = by * 128;
    int phase = by & (NSTEP - 1);

    f32x4 acc[4][4];
#pragma unroll
    for (int m = 0; m < 4; m++)
#pragma unroll
      for (int n = 0; n < 4; n++) acc[m][n] = (f32x4){0.f, 0.f, 0.f, 0.f};

    for (int tt = 0; tt < NSTEP; tt++) {
      int t = tt + phase; if (t >= NSTEP) t -= NSTEP;
      int k0 = t * 64;
      __syncthreads();
#pragma unroll
      for (int i4 = 0; i4 < 4; i4++) {
        int i = i4 * 4 + w;
        int row = i * 8 + (l >> 3);
        int sc = (l & 7) ^ (row & 7);
        gl_lds16(Wv + (long)(n0 + row) * K + k0 + sc * 8, Bs + i * 1024 + l * 16);
      }
#pragma unroll
      for (int i4 = 0; i4 < 8; i4++) {
        int i = i4 * 4 + w;
        int row = i * 4 + (l >> 4);
        int g = m0 + row; if (g >= MVAL) g = MVAL - 1;
        int sc = (l & 15) ^ (row & 15);
        gl_lds16(memory + (long)g * K + k0 + sc * 4, As + i * 1024 + l * 16);
      }
      __syncthreads();
#pragma unroll
      for (int sk = 0; sk < 2; sk++) {
        bf16x8 af[4], bfr[4];
#pragma unroll
        for (int m = 0; m < 4; m++) {
          int row = wr * 64 + m * 16 + lr;
          int ca = (sk * 8 + lg * 2) ^ (row & 15);
          int cb = (sk * 8 + lg * 2 + 1) ^ (row & 15);
          f32x4 fa = *(const f32x4*)(As + row * 256 + ca * 16);
          f32x4 fb = *(const f32x4*)(As + row * 256 + cb * 16);
          bf16x8 v;
          v[0] = (short)f2bf(fa[0]); v[1] = (short)f2bf(fa[1]);
          v[2] = (short)f2bf(fa[2]); v[3] = (short)f2bf(fa[3]);
          v[4] = (short)f2bf(fb[0]); v[5] = (short)f2bf(fb[1]);
          v[6] = (short)f2bf(fb[2]); v[7] = (short)f2bf(fb[3]);
          af[m] = v;
        }
#pragma unroll
        for (int n = 0; n < 4; n++) {
          int row = wc * 64 + n * 16 + lr;
          int c = (sk * 4 + lg) ^ (row & 7);
          bfr[n] = *(const bf16x8*)(Bs + row * 128 + c * 16);
        }
#pragma unroll
        for (int m = 0; m < 4; m++)
#pragma unroll
          for (int n = 0; n < 4; n++)
            acc[m][n] = __builtin_amdgcn_mfma_f32_16x16x32_bf16(af[m], bfr[n], acc[m][n], 0, 0, 0);
      }
    }

    float bv[4];
#pragma unroll
    for (int ni = 0; ni < 4; ni++) bv[ni] = bval[n0 + wc * 64 + ni * 16 + lr];
#pragma unroll
    for (int mi = 0; mi < 4; mi++) {
#pragma unroll
      for (int r = 0; r < 4; r++) {
        int row = m0 + wr * 64 + mi * 16 + lg * 4 + r;
        if (row < MVAL) {
#pragma unroll
          for (int ni = 0; ni < 4; ni++) {
            int col = n0 + wc * 64 + ni * 16 + lr;
            Cv[(long)row * 256 + col] = f2bf(acc[mi][ni][r] + bv[ni]);
          }
        }
      }
    }
  } else {
    // ---------------- XCD-clustered flash attention path ----------------
    unsigned short (*Vt)[72] = (unsigned short(*)[72])smem;              // 4608 B
    unsigned short (*Ps)[16][72] = (unsigned short(*)[16][72])(smem + 4608); // 9216 B
    int bid = blockIdx.x - NVB;
    int xcd = bid & 7;
    int rest = bid >> 3;
    int pgrp = rest / 15;
    int qt   = rest - pgrp * 15;
    int pair = pgrp * 8 + xcd;
    int q0 = qt * 64;
    int h = pair & 7, b = pair >> 3;
    const float scale = 0.17677669529663687f;

    int qrow = q0 + w * 16 + lr;
    int qclamp = qrow < 899 ? qrow : 899;
    bf16x8 qf = *(const bf16x8*)(qkv + ((long)qclamp * 8 + b) * 768 + h * 32 + lg * 8);

    f32x4 o_acc[2];
    o_acc[0] = (f32x4){0.f, 0.f, 0.f, 0.f};
    o_acc[1] = (f32x4){0.f, 0.f, 0.f, 0.f};
    float m_run[4] = {-1e30f, -1e30f, -1e30f, -1e30f};
    float l_run[4] = {0.f, 0.f, 0.f, 0.f};

    for (int k0 = 0; k0 < NQ; k0 += 64) {
      __syncthreads();
      {
        int key = tid >> 2, dg = tid & 3;
        int kk = k0 + key; if (kk > 899) kk = 899;
        bf16x8 vv = *(const bf16x8*)(qkv + ((long)kk * 8 + b) * 768 + 512 + h * 32 + dg * 8);
#pragma unroll
        for (int j = 0; j < 8; j++) Vt[dg * 8 + j][key] = (unsigned short)vv[j];
      }
      f32x4 sg[4];
#pragma unroll
      for (int ng = 0; ng < 4; ng++) {
        int key = k0 + ng * 16 + lr; int kc = key < 899 ? key : 899;
        bf16x8 kf = *(const bf16x8*)(qkv + ((long)kc * 8 + b) * 768 + 256 + h * 32 + lg * 8);
        sg[ng] = __builtin_amdgcn_mfma_f32_16x16x32_bf16(qf, kf, (f32x4){0.f, 0.f, 0.f, 0.f}, 0, 0, 0);
      }
      float sv[4][4];
#pragma unroll
      for (int ng = 0; ng < 4; ng++) {
        bool bad = (k0 + ng * 16 + lr) >= NQ;
#pragma unroll
        for (int r = 0; r < 4; r++) sv[ng][r] = bad ? -1e30f : sg[ng][r] * scale;
      }
      float p[4][4];
#pragma unroll
      for (int r = 0; r < 4; r++) {
        float rmax = fmaxf(fmaxf(sv[0][r], sv[1][r]), fmaxf(sv[2][r], sv[3][r]));
#pragma unroll
        for (int mk = 8; mk; mk >>= 1) rmax = fmaxf(rmax, __shfl_xor(rmax, mk));
        float mnew = fmaxf(m_run[r], rmax);
        float fs = __expf(m_run[r] - mnew);
        m_run[r] = mnew;
        float ps = 0.f;
#pragma unroll
        for (int ng = 0; ng < 4; ng++) { p[ng][r] = __expf(sv[ng][r] - mnew); ps += p[ng][r]; }
#pragma unroll
        for (int mk = 8; mk; mk >>= 1) ps += __shfl_xor(ps, mk);
        l_run[r] = l_run[r] * fs + ps;
        o_acc[0][r] *= fs;
        o_acc[1][r] *= fs;
      }
#pragma unroll
      for (int ng = 0; ng < 4; ng++)
#pragma unroll
        for (int r = 0; r < 4; r++)
          Ps[w][lg * 4 + r][lr + ng * 16] = f2bf(p[ng][r]);
      __syncthreads();
#pragma unroll
      for (int ks = 0; ks < 2; ks++) {
        bf16x8 pf = *(const bf16x8*)&Ps[w][lr][ks * 32 + lg * 8];
#pragma unroll
        for (int ni = 0; ni < 2; ni++) {
          bf16x8 vf = *(const bf16x8*)&Vt[ni * 16 + lr][ks * 32 + lg * 8];
          o_acc[ni] = __builtin_amdgcn_mfma_f32_16x16x32_bf16(pf, vf, o_acc[ni], 0, 0, 0);
        }
      }
    }
#pragma unroll
    for (int r = 0; r < 4; r++) {
      int orow = q0 + w * 16 + lg * 4 + r;
      if (orow < NQ) {
        float inv = 1.f / l_run[r];
        unsigned short* op = out + ((long)orow * 8 + b) * 256 + h * 32 + lr;
        op[0]  = f2bf(o_acc[0][r] * inv);
        op[16] = f2bf(o_acc[1][r] * inv);
      }
    }
  }
}

// ---------------- template GEMM (R11 gemm_s) ----------------
template <int AF32, int OUT_BF16, int RELU, int NSTEP>
__global__ __launch_bounds__(256, 4) void gemm_s_kernel(
    const void* __restrict__ Araw, const unsigned short* __restrict__ W,
    const float* __restrict__ bias, void* __restrict__ C,
    int M, int ldc) {
  constexpr int K = NSTEP * 64;
  constexpr int ABYTES = AF32 ? 32768 : 16384;
  __shared__ alignas(16) unsigned char As[ABYTES];
  __shared__ alignas(16) unsigned char Bs[16384];
  int tid = threadIdx.x;
  int l = tid & 63, w = tid >> 6;
  int lr = l & 15, lg = l >> 4;
  int wr = w >> 1, wc = w & 1;
  int n0 = blockIdx.x * 128, m0 = blockIdx.y * 128;
  int phase = blockIdx.y & (NSTEP - 1);

  f32x4 acc[4][4];
#pragma unroll
  for (int m = 0; m < 4; m++)
#pragma unroll
    for (int n = 0; n < 4; n++) acc[m][n] = (f32x4){0.f, 0.f, 0.f, 0.f};

  for (int tt = 0; tt < NSTEP; tt++) {
    int t = tt + phase; if (t >= NSTEP) t -= NSTEP;
    int k0 = t * 64;
    __syncthreads();
#pragma unroll
    for (int i4 = 0; i4 < 4; i4++) {
      int i = i4 * 4 + w;
      int row = i * 8 + (l >> 3);
      int sc = (l & 7) ^ (row & 7);
      gl_lds16(W + (long)(n0 + row) * K + k0 + sc * 8, Bs + i * 1024 + l * 16);
    }
    if (AF32) {
      const float* Af = (const float*)Araw;
#pragma unroll
      for (int i4 = 0; i4 < 8; i4++) {
        int i = i4 * 4 + w;
        int row = i * 4 + (l >> 4);
        int g = m0 + row; if (g >= M) g = M - 1;
        int sc = (l & 15) ^ (row & 15);
        gl_lds16(Af + (long)g * K + k0 + sc * 4, As + i * 1024 + l * 16);
      }
    } else {
      const unsigned short* A = (const unsigned short*)Araw;
#pragma unroll
      for (int i4 = 0; i4 < 4; i4++) {
        int i = i4 * 4 + w;
        int row = i * 8 + (l >> 3);
        int g = m0 + row; if (g >= M) g = M - 1;
        int sc = (l & 7) ^ (row & 7);
        gl_lds16(A + (long)g * K + k0 + sc * 8, As + i * 1024 + l * 16);
      }
    }
    __syncthreads();
#pragma unroll
    for (int sk = 0; sk < 2; sk++) {
      bf16x8 af[4], bfr[4];
      if (AF32) {
#pragma unroll
        for (int m = 0; m < 4; m++) {
          int row = wr * 64 + m * 16 + lr;
          int ca = (sk * 8 + lg * 2) ^ (row & 15);
          int cb = (sk * 8 + lg * 2 + 1) ^ (row & 15);
          f32x4 fa = *(const f32x4*)(As + row * 256 + ca * 16);
          f32x4 fb = *(const f32x4*)(As + row * 256 + cb * 16);
          bf16x8 v;
          v[0] = (short)f2bf(fa[0]); v[1] = (short)f2bf(fa[1]);
          v[2] = (short)f2bf(fa[2]); v[3] = (short)f2bf(fa[3]);
          v[4] = (short)f2bf(fb[0]); v[5] = (short)f2bf(fb[1]);
          v[6] = (short)f2bf(fb[2]); v[7] = (short)f2bf(fb[3]);
          af[m] = v;
        }
      } else {
#pragma unroll
        for (int m = 0; m < 4; m++) {
          int row = wr * 64 + m * 16 + lr;
          int c = (sk * 4 + lg) ^ (row & 7);
          af[m] = *(const bf16x8*)(As + row * 128 + c * 16);
        }
      }
#pragma unroll
      for (int n = 0; n < 4; n++) {
        int row = wc * 64 + n * 16 + lr;
        int c = (sk * 4 + lg) ^ (row & 7);
        bfr[n] = *(const bf16x8*)(Bs + row * 128 + c * 16);
      }
#pragma unroll
      for (int m = 0; m < 4; m++)
#pragma unroll
        for (int n = 0; n < 4; n++)
          acc[m][n] = __builtin_amdgcn_mfma_f32_16x16x32_bf16(af[m], bfr[n], acc[m][n], 0, 0, 0);
    }
  }

  float bv[4];
#pragma unroll
  for (int ni = 0; ni < 4; ni++) bv[ni] = bias[n0 + wc * 64 + ni * 16 + lr];
#pragma unroll
  for (int mi = 0; mi < 4; mi++) {
#pragma unroll
    for (int r = 0; r < 4; r++) {
      int row = m0 + wr * 64 + mi * 16 + lg * 4 + r;
      if (row < M) {
#pragma unroll
        for (int ni = 0; ni < 4; ni++) {
          int col = n0 + wc * 64 + ni * 16 + lr;
          float v = acc[mi][ni][r] + bv[ni];
          if (RELU) v = fmaxf(v, 0.f);
          if (OUT_BF16) ((unsigned short*)C)[(long)row * ldc + col] = f2bf(v);
          else          ((float*)C)[(long)row * ldc + col] = v;
        }
      }
    }
  }
}

// ---------------- bilinear sampler v4: image-clustered blocks, 16 tokens/block ----------------
__device__ __forceinline__ void fetch16_acc(const unsigned short* __restrict__ vtmp, int lo, int W,
                                            int yi, int xi, int b, int col0, float wgt,
                                            float* a) {
  if ((xi < 0) | (xi >= W) | (yi < 0) | (yi >= W)) return;
  const unsigned short* p = vtmp + ((long)((lo + yi * W + xi) * BSZ + b)) * 256 + col0;
  bf16x8 r0 = *(const bf16x8*)p;
  bf16x8 r1 = *(const bf16x8*)(p + 8);
#pragma unroll
  for (int j = 0; j < 8; j++) a[j] += wgt * bf2f((unsigned short)r0[j]);
#pragma unroll
  for (int j = 0; j < 8; j++) a[8 + j] += wgt * bf2f((unsigned short)r1[j]);
}

__global__ __launch_bounds__(256) void sampler_kernel(const unsigned short* __restrict__ vtmp,
                                                      const float* __restrict__ oa,
                                                      const float* __restrict__ ref,
                                                      unsigned short* __restrict__ samp) {
  __shared__ float s_off[16][256];
  __shared__ float s_aw[16][128];
  __shared__ float s_ref[16][8];
  int tid = threadIdx.x;
  int bid = blockIdx.x;
  int img = bid & 7;
  int jb  = bid >> 3;
  int qi0 = jb * 16;
#pragma unroll
  for (int k = 0; k < 16; k++) {
    int qi = qi0 + k; if (qi > 899) qi = 899;
    long t = (long)qi * 8 + img;
    s_off[k][tid] = oa[t * 384 + tid];
  }
#pragma unroll
  for (int i = 0; i < 8; i++) {
    int idx = i * 256 + tid;
    int k = idx >> 7, c = idx & 127;
    int qi = qi0 + k; if (qi > 899) qi = 899;
    long t = (long)qi * 8 + img;
    s_aw[k][c] = oa[t * 384 + 256 + c];
  }
  if (tid < 128) {
    int k = tid >> 3;
    int qi = qi0 + k; if (qi > 899) qi = 899;
    long t = (long)qi * 8 + img;
    s_ref[k][tid & 7] = ref[t * 8 + (tid & 7)];
  }
  __syncthreads();
  if (tid < 128) {
    int k = tid >> 3, hh = tid & 7;
    float* p = &s_aw[k][hh * 16];
    float m = -1e30f;
#pragma unroll
    for (int j = 0; j < 16; j++) m = fmaxf(m, p[j]);
    float s = 0.f;
#pragma unroll
    for (int j = 0; j < 16; j++) { p[j] = __expf(p[j] - m); s += p[j]; }
    float inv = 1.f / s;
#pragma unroll
    for (int j = 0; j < 16; j++) p[j] *= inv;
  }
  __syncthreads();
  int w = tid >> 4;
  int l = tid & 15;
  int qi = qi0 + w;
  int h = l >> 1, col0 = h * 32 + (l & 1) * 16;
  int b = img;
  const int Wls[4]  = {100, 50, 25, 13};
  const int lofs[4] = {0, 10000, 12500, 13125};
  float a[16];
#pragma unroll
  for (int j = 0; j < 16; j++) a[j] = 0.f;
#pragma unroll
  for (int lvl = 0; lvl < 4; lvl++) {
    int W = Wls[lvl];
    float Wf = (float)W;
    int lo = lofs[lvl];
    float rx = s_ref[w][lvl * 2 + 0], ry = s_ref[w][lvl * 2 + 1];
#pragma unroll
    for (int p = 0; p < 4; p++) {
      float ox = s_off[w][((h * 4 + lvl) * 4 + p) * 2 + 0];
      float oy = s_off[w][((h * 4 + lvl) * 4 + p) * 2 + 1];
      float x = rx * Wf + ox - 0.5f;
      float y = ry * Wf + oy - 0.5f;
      float x0f = floorf(x), y0f = floorf(y);
      float fx = x - x0f, fy = y - y0f;
      int x0 = (int)x0f, y0 = (int)y0f;
      float aa = s_aw[w][h * 16 + lvl * 4 + p];
      float w00 = aa * (1.f - fx) * (1.f - fy);
      float w01 = aa * fx * (1.f - fy);
      float w10 = aa * (1.f - fx) * fy;
      float w11 = aa * fx * fy;
      fetch16_acc(vtmp, lo, W, y0,     x0,     b, col0, w00, a);
      fetch16_acc(vtmp, lo, W, y0,     x0 + 1, b, col0, w01, a);
      fetch16_acc(vtmp, lo, W, y0 + 1, x0,     b, col0, w10, a);
      fetch16_acc(vtmp, lo, W, y0 + 1, x0 + 1, b, col0, w11, a);
    }
  }
  if (qi < NQ) {
    long t = (long)qi * 8 + img;
    bf16x8 o0, o1;
#pragma unroll
    for (int j = 0; j < 8; j++) { o0[j] = (short)f2bf(a[j]); o1[j] = (short)f2bf(a[8 + j]); }
    *(bf16x8*)(samp + t * 256 + col0) = o0;
    *(bf16x8*)(samp + t * 256 + col0 + 8) = o1;
  }
}

// ---------------- LayerNorm(x + res); optional bf16 out; optional bf16(out+pos) ----------------
__global__ __launch_bounds__(256) void ln_kernel(const float* __restrict__ x,
                                                 const float* __restrict__ res,
                                                 const float* __restrict__ w,
                                                 const float* __restrict__ bvec,
                                                 float* __restrict__ out,
                                                 unsigned short* __restrict__ out_bf,
                                                 const float* __restrict__ pos,
                                                 unsigned short* __restrict__ pos_bf,
                                                 int rows) {
  int wv = threadIdx.x >> 6, lane = threadIdx.x & 63;
  int row = blockIdx.x * 4 + wv;
  if (row >= rows) return;
  float4 xv = *(const float4*)(x + (long)row * 256 + lane * 4);
  float4 rv = *(const float4*)(res + (long)row * 256 + lane * 4);
  float v0 = xv.x + rv.x, v1 = xv.y + rv.y, v2 = xv.z + rv.z, v3 = xv.w + rv.w;
  float s = v0 + v1 + v2 + v3;
#pragma unroll
  for (int o = 32; o; o >>= 1) s += __shfl_xor(s, o);
  float mean = s * (1.f / 256.f);
  float d0 = v0 - mean, d1 = v1 - mean, d2 = v2 - mean, d3 = v3 - mean;
  float q = d0 * d0 + d1 * d1 + d2 * d2 + d3 * d3;
#pragma unroll
  for (int o = 32; o; o >>= 1) q += __shfl_xor(q, o);
  float rstd = rsqrtf(q * (1.f / 256.f) + 1e-5f);
  float4 wv4 = *(const float4*)(w + lane * 4);
  float4 bv4 = *(const float4*)(bvec + lane * 4);
  float o0 = d0 * rstd * wv4.x + bv4.x;
  float o1 = d1 * rstd * wv4.y + bv4.y;
  float o2 = d2 * rstd * wv4.z + bv4.z;
  float o3 = d3 * rstd * wv4.w + bv4.w;
  *(float4*)(out + (long)row * 256 + lane * 4) = make_float4(o0, o1, o2, o3);
  if (out_bf) {
    unsigned short* p = out_bf + (long)row * 256 + lane * 4;
    p[0] = f2bf(o0); p[1] = f2bf(o1); p[2] = f2bf(o2); p[3] = f2bf(o3);
  }
  if (pos_bf) {
    float4 pv = *(const float4*)(pos + (long)row * 256 + lane * 4);
    unsigned short* p = pos_bf + (long)row * 256 + lane * 4;
    p[0] = f2bf(o0 + pv.x); p[1] = f2bf(o1 + pv.y);
    p[2] = f2bf(o2 + pv.z); p[3] = f2bf(o3 + pv.w);
  }
}

extern "C" void kernel_launch(void* const* d_in, const int* in_sizes, int n_in,
                              void* d_out, int out_size, void* d_ws, size_t ws_size,
                              hipStream_t stream) {
  const float* tgt     = (const float*)d_in[0];
  const float* pos     = (const float*)d_in[1];
  const float* refpts  = (const float*)d_in[2];
  const float* memory  = (const float*)d_in[3];
  const float* sa_Wqkv = (const float*)d_in[4];
  const float* sa_bqkv = (const float*)d_in[5];
  const float* sa_Wo   = (const float*)d_in[6];
  const float* sa_bo   = (const float*)d_in[7];
  const float* ln1_w   = (const float*)d_in[8];
  const float* ln1_b   = (const float*)d_in[9];
  const float* ln2_w   = (const float*)d_in[10];
  const float* ln2_b   = (const float*)d_in[11];
  const float* ln3_w   = (const float*)d_in[12];
  const float* ln3_b   = (const float*)d_in[13];
  const float* ca_Woff = (const float*)d_in[14];
  const float* ca_boff = (const float*)d_in[15];
  const float* ca_Wattn= (const float*)d_in[16];
  const float* ca_battn= (const float*)d_in[17];
  const float* ca_Wval = (const float*)d_in[18];
  const float* ca_bval = (const float*)d_in[19];
  const float* ca_Wout = (const float*)d_in[20];
  const float* ca_bout = (const float*)d_in[21];
  const float* ffn_W1  = (const float*)d_in[22];
  const float* ffn_b1  = (const float*)d_in[23];
  const float* ffn_W2  = (const float*)d_in[24];
  const float* ffn_b2  = (const float*)d_in[25];

  char* ws = (char*)d_ws;
  float*          buf_ca = (float*)(ws);
  float*          buf_t3 = (float*)(ws + 8388608);
  unsigned short* t3_bf  = (unsigned short*)(ws + 16777216);
  unsigned short* buf_h  = (unsigned short*)(ws + 20971520);
  float*          buf_f  = (float*)(ws + 36700160);
  float*          bias_cat = (float*)(ws + 44072960);
  unsigned short* buf_v  = (unsigned short*)(ws + 54452224);
  unsigned short* wts    = (unsigned short*)(ws + 112590848);
  unsigned short* buf_q  = (unsigned short*)(ws + 114622464);
  unsigned short* buf_qkv= (unsigned short*)(ws + 118308864);
  float*          buf_oa = (float*)(ws + 118308864);
  unsigned short* buf_o  = (unsigned short*)(ws + 129368064);
  unsigned short* buf_smp= (unsigned short*)(ws + 129368064);
  float*          buf_t2 = (float*)(ws + 133054464);

  const unsigned short* w_qkv = wts + 0;
  const unsigned short* w_o   = wts + 196608;
  const unsigned short* w_val = wts + 262144;
  const unsigned short* w_oa  = wts + 327680;
  const unsigned short* w_out = wts + 425984;
  const unsigned short* w_f1  = wts + 491520;
  const unsigned short* w_f2  = wts + 753664;

  dim3 blk(256);

  // 1. fused prep: weights cast + q=tgt+pos + bias concat
  prep_kernel<<<1398, blk, 0, stream>>>(sa_Wqkv, sa_Wo, ca_Wval, ca_Woff, ca_Wattn,
                                        ca_Wout, ffn_W1, ffn_W2, wts,
                                        tgt, pos, buf_q, ca_boff, ca_battn, bias_cat);

  // 2. batched qk + v-part GEMMs (ops 1,2 of the descriptor; op 0 unused)
  B3 ops;
  ops.A[0] = buf_q;    ops.W[0] = w_qkv;           ops.bias[0] = sa_bqkv;      ops.C[0] = buf_qkv;
  ops.M[0] = NTOK;     ops.ldc[0] = 768;           ops.af32[0] = 0;            ops.nx[0] = 4;
  ops.A[1] = buf_q;    ops.W[1] = w_qkv;           ops.bias[1] = sa_bqkv;      ops.C[1] = buf_qkv;
  ops.M[1] = NTOK;     ops.ldc[1] = 768;           ops.af32[1] = 0;            ops.nx[1] = 4;
  ops.A[2] = tgt;      ops.W[2] = w_qkv + 512*256; ops.bias[2] = sa_bqkv + 512; ops.C[2] = buf_qkv + 512;
  ops.M[2] = NTOK;     ops.ldc[2] = 768;           ops.af32[2] = 1;            ops.nx[2] = 2;
  ops.blk0[0] = 0; ops.blk0[1] = 0; ops.blk0[2] = 228;
  gemm_batch3_kernel<<<342, blk, 0, stream>>>(ops);

  // 3. HETEROGENEOUS: value projection GEMM (1662 blocks) ∥ flash attention (960 blocks)
  value_attn_kernel<<<NVB + 960, blk, 0, stream>>>(memory, w_val, ca_bval, buf_v,
                                                   buf_qkv, buf_o);

  // 4. o @ Wo^T (f32 out) -> buf_t2
  gemm_s_kernel<0, 0, 0, 4><<<dim3(2, 57), blk, 0, stream>>>(buf_o, w_o, sa_bo,
                                                             buf_t2, NTOK, 256);
  // 5. t2 = LN2(g6 + tgt) in place; also q2_bf = bf16(t2 + pos)
  ln_kernel<<<1800, blk, 0, stream>>>(buf_t2, tgt, ln2_w, ln2_b, buf_t2, nullptr,
                                      pos, buf_q, NTOK);
  // 6. offsets + attention logits fused: [7200,384] (f32, ldc 384)
  gemm_s_kernel<0, 0, 0, 4><<<dim3(3, 57), blk, 0, stream>>>(buf_q, w_oa, bias_cat,
                                                             buf_oa, NTOK, 384);
  // 7. bilinear sampling (image-clustered; softmax fused; bf16 out)
  sampler_kernel<<<456, blk, 0, stream>>>(buf_v, buf_oa, refpts, buf_smp);
  // 8. ca = samp @ Wout^T (f32)
  gemm_s_kernel<0, 0, 0, 4><<<dim3(2, 57), blk, 0, stream>>>(buf_smp, w_out, ca_bout,
                                                             buf_ca, NTOK, 256);
  // 9. t3 = LN1(ca + t2), f32 + bf16
  ln_kernel<<<1800, blk, 0, stream>>>(buf_ca, buf_t2, ln1_w, ln1_b, buf_t3, t3_bf,
                                      nullptr, nullptr, NTOK);
  // 10. h = relu(t3 @ W1^T) (bf16)
  gemm_s_kernel<0, 1, 1, 4><<<dim3(8, 57), blk, 0, stream>>>(t3_bf, w_f1, ffn_b1,
                                                             buf_h, NTOK, 1024);
  // 11. f = h @ W2^T (f32), K=1024
  gemm_s_kernel<0, 0, 0, 16><<<dim3(2, 57), blk, 0, stream>>>(buf_h, w_f2, ffn_b2,
                                                              buf_f, NTOK, 256);
  // 12. out = LN3(f + t3)
  ln_kernel<<<1800, blk, 0, stream>>>(buf_f, buf_t3, ln3_w, ln3_b, (float*)d_out, nullptr,
                                      nullptr, nullptr, NTOK);
}

// Round 20
// 213.241 us; speedup vs baseline: 1.0407x; 1.0407x over previous
//
#include <hip/hip_runtime.h>
#include <hip/hip_bf16.h>

#define NQ   900
#define BSZ  8
#define DM   256
#define NH   8
#define DHD  32
#define DFF_ 1024
#define LVTOT 13294
#define NTOK (NQ*BSZ)    // 7200
#define MVAL (LVTOT*BSZ) // 106352

typedef __attribute__((ext_vector_type(8))) short bf16x8;
typedef __attribute__((ext_vector_type(4))) short bf16x4;
typedef __attribute__((ext_vector_type(4))) float f32x4;
typedef unsigned int u32;

__device__ __forceinline__ unsigned short f2bf(float x) {
  union { __hip_bfloat16 h; unsigned short u; } cv;
  cv.h = __float2bfloat16(x);
  return cv.u;
}
__device__ __forceinline__ float bf2f(unsigned short u) {
  union { __hip_bfloat16 h; unsigned short u; } cv;
  cv.u = u;
  return __bfloat162float(cv.h);
}

__device__ __forceinline__ void gl_lds16(const void* gsrc, void* ldst) {
  __builtin_amdgcn_global_load_lds(
      (const __attribute__((address_space(1))) u32*)gsrc,
      (__attribute__((address_space(3))) u32*)ldst, 16, 0, 0);
}

// ---------------- fused prep: weights-cast ++ addcast(q=tgt+pos) ++ bias-concat ----------------
__global__ __launch_bounds__(256) void prep_kernel(
    const float* p0, const float* p1, const float* p2, const float* p3,
    const float* p4, const float* p5, const float* p6, const float* p7,
    unsigned short* wdst,
    const float* a, const float* b, unsigned short* qdst,
    const float* boff, const float* battn, float* bcat) {
  int bid = blockIdx.x, tid = threadIdx.x;
  if (bid < 496) {
    long i8 = ((long)bid * 256 + tid) * 8;
    const float* src; long off;
    if      (i8 < 196608) { src = p0; off = i8; }
    else if (i8 < 262144) { src = p1; off = i8 - 196608; }
    else if (i8 < 327680) { src = p2; off = i8 - 262144; }
    else if (i8 < 393216) { src = p3; off = i8 - 327680; }
    else if (i8 < 425984) { src = p4; off = i8 - 393216; }
    else if (i8 < 491520) { src = p5; off = i8 - 425984; }
    else if (i8 < 753664) { src = p6; off = i8 - 491520; }
    else                  { src = p7; off = i8 - 753664; }
    float4 x = *(const float4*)(src + off);
    float4 y = *(const float4*)(src + off + 4);
    bf16x8 v;
    v[0] = (short)f2bf(x.x); v[1] = (short)f2bf(x.y);
    v[2] = (short)f2bf(x.z); v[3] = (short)f2bf(x.w);
    v[4] = (short)f2bf(y.x); v[5] = (short)f2bf(y.y);
    v[6] = (short)f2bf(y.z); v[7] = (short)f2bf(y.w);
    *(bf16x8*)(wdst + i8) = v;
  } else if (bid < 496 + 900) {
    int i = (bid - 496) * 256 + tid;
    float4 a0 = ((const float4*)a)[i * 2], a1 = ((const float4*)a)[i * 2 + 1];
    float4 b0 = ((const float4*)b)[i * 2], b1 = ((const float4*)b)[i * 2 + 1];
    bf16x8 v;
    v[0] = (short)f2bf(a0.x + b0.x); v[1] = (short)f2bf(a0.y + b0.y);
    v[2] = (short)f2bf(a0.z + b0.z); v[3] = (short)f2bf(a0.w + b0.w);
    v[4] = (short)f2bf(a1.x + b1.x); v[5] = (short)f2bf(a1.y + b1.y);
    v[6] = (short)f2bf(a1.z + b1.z); v[7] = (short)f2bf(a1.w + b1.w);
    *(bf16x8*)(qdst + (long)i * 8) = v;
  } else {
    int i = (bid - 1396) * 256 + tid;
    if (i < 256) bcat[i] = boff[i];
    else if (i < 384) bcat[i] = battn[i - 256];
  }
}

// ---------------- batched stage-1 GEMM: 3 ops (value, qk, v-part), K=256 ----------------
struct B3 {
  const void* A[3];
  const unsigned short* W[3];
  const float* bias[3];
  void* C[3];
  int M[3], ldc[3], af32[3], blk0[3], nx[3];
};

__global__ __launch_bounds__(256, 4) void gemm_batch3_kernel(B3 ops) {
  constexpr int K = 256, NSTEP = 4;
  __shared__ alignas(16) unsigned char As[32768];
  __shared__ alignas(16) unsigned char Bs[16384];
  int bid = blockIdx.x;
  int oi = (bid >= ops.blk0[2]) ? 2 : (bid >= ops.blk0[1] ? 1 : 0);
  int rel = bid - ops.blk0[oi];
  int nx = ops.nx[oi];
  int bx = rel % nx, by = rel / nx;
  const void* Araw = ops.A[oi];
  const unsigned short* W = ops.W[oi];
  const float* bias = ops.bias[oi];
  void* C = ops.C[oi];
  int M = ops.M[oi], ldc = ops.ldc[oi], AF32 = ops.af32[oi];

  int tid = threadIdx.x;
  int l = tid & 63, w = tid >> 6;
  int lr = l & 15, lg = l >> 4;
  int wr = w >> 1, wc = w & 1;
  int n0 = bx * 128, m0 = by * 128;
  int phase = by & (NSTEP - 1);

  f32x4 acc[4][4];
#pragma unroll
  for (int m = 0; m < 4; m++)
#pragma unroll
    for (int n = 0; n < 4; n++) acc[m][n] = (f32x4){0.f, 0.f, 0.f, 0.f};

  for (int tt = 0; tt < NSTEP; tt++) {
    int t = tt + phase; if (t >= NSTEP) t -= NSTEP;
    int k0 = t * 64;
    __syncthreads();
#pragma unroll
    for (int i4 = 0; i4 < 4; i4++) {
      int i = i4 * 4 + w;
      int row = i * 8 + (l >> 3);
      int sc = (l & 7) ^ (row & 7);
      gl_lds16(W + (long)(n0 + row) * K + k0 + sc * 8, Bs + i * 1024 + l * 16);
    }
    if (AF32) {
      const float* Af = (const float*)Araw;
#pragma unroll
      for (int i4 = 0; i4 < 8; i4++) {
        int i = i4 * 4 + w;
        int row = i * 4 + (l >> 4);
        int g = m0 + row; if (g >= M) g = M - 1;
        int sc = (l & 15) ^ (row & 15);
        gl_lds16(Af + (long)g * K + k0 + sc * 4, As + i * 1024 + l * 16);
      }
    } else {
      const unsigned short* A = (const unsigned short*)Araw;
#pragma unroll
      for (int i4 = 0; i4 < 4; i4++) {
        int i = i4 * 4 + w;
        int row = i * 8 + (l >> 3);
        int g = m0 + row; if (g >= M) g = M - 1;
        int sc = (l & 7) ^ (row & 7);
        gl_lds16(A + (long)g * K + k0 + sc * 8, As + i * 1024 + l * 16);
      }
    }
    __syncthreads();
#pragma unroll
    for (int sk = 0; sk < 2; sk++) {
      bf16x8 af[4], bfr[4];
      if (AF32) {
#pragma unroll
        for (int m = 0; m < 4; m++) {
          int row = wr * 64 + m * 16 + lr;
          int ca = (sk * 8 + lg * 2) ^ (row & 15);
          int cb = (sk * 8 + lg * 2 + 1) ^ (row & 15);
          f32x4 fa = *(const f32x4*)(As + row * 256 + ca * 16);
          f32x4 fb = *(const f32x4*)(As + row * 256 + cb * 16);
          bf16x8 v;
          v[0] = (short)f2bf(fa[0]); v[1] = (short)f2bf(fa[1]);
          v[2] = (short)f2bf(fa[2]); v[3] = (short)f2bf(fa[3]);
          v[4] = (short)f2bf(fb[0]); v[5] = (short)f2bf(fb[1]);
          v[6] = (short)f2bf(fb[2]); v[7] = (short)f2bf(fb[3]);
          af[m] = v;
        }
      } else {
#pragma unroll
        for (int m = 0; m < 4; m++) {
          int row = wr * 64 + m * 16 + lr;
          int c = (sk * 4 + lg) ^ (row & 7);
          af[m] = *(const bf16x8*)(As + row * 128 + c * 16);
        }
      }
#pragma unroll
      for (int n = 0; n < 4; n++) {
        int row = wc * 64 + n * 16 + lr;
        int c = (sk * 4 + lg) ^ (row & 7);
        bfr[n] = *(const bf16x8*)(Bs + row * 128 + c * 16);
      }
#pragma unroll
      for (int m = 0; m < 4; m++)
#pragma unroll
        for (int n = 0; n < 4; n++)
          acc[m][n] = __builtin_amdgcn_mfma_f32_16x16x32_bf16(af[m], bfr[n], acc[m][n], 0, 0, 0);
    }
  }

  float bv[4];
#pragma unroll
  for (int ni = 0; ni < 4; ni++) bv[ni] = bias[n0 + wc * 64 + ni * 16 + lr];
#pragma unroll
  for (int mi = 0; mi < 4; mi++) {
#pragma unroll
    for (int r = 0; r < 4; r++) {
      int row = m0 + wr * 64 + mi * 16 + lg * 4 + r;
      if (row < M) {
#pragma unroll
        for (int ni = 0; ni < 4; ni++) {
          int col = n0 + wc * 64 + ni * 16 + lr;
          ((unsigned short*)C)[(long)row * ldc + col] = f2bf(acc[mi][ni][r] + bv[ni]);
        }
      }
    }
  }
}

// ---------------- template GEMM (R11 gemm_s) ----------------
template <int AF32, int OUT_BF16, int RELU, int NSTEP>
__global__ __launch_bounds__(256, 4) void gemm_s_kernel(
    const void* __restrict__ Araw, const unsigned short* __restrict__ W,
    const float* __restrict__ bias, void* __restrict__ C,
    int M, int ldc) {
  constexpr int K = NSTEP * 64;
  constexpr int ABYTES = AF32 ? 32768 : 16384;
  __shared__ alignas(16) unsigned char As[ABYTES];
  __shared__ alignas(16) unsigned char Bs[16384];
  int tid = threadIdx.x;
  int l = tid & 63, w = tid >> 6;
  int lr = l & 15, lg = l >> 4;
  int wr = w >> 1, wc = w & 1;
  int n0 = blockIdx.x * 128, m0 = blockIdx.y * 128;
  int phase = blockIdx.y & (NSTEP - 1);

  f32x4 acc[4][4];
#pragma unroll
  for (int m = 0; m < 4; m++)
#pragma unroll
    for (int n = 0; n < 4; n++) acc[m][n] = (f32x4){0.f, 0.f, 0.f, 0.f};

  for (int tt = 0; tt < NSTEP; tt++) {
    int t = tt + phase; if (t >= NSTEP) t -= NSTEP;
    int k0 = t * 64;
    __syncthreads();
#pragma unroll
    for (int i4 = 0; i4 < 4; i4++) {
      int i = i4 * 4 + w;
      int row = i * 8 + (l >> 3);
      int sc = (l & 7) ^ (row & 7);
      gl_lds16(W + (long)(n0 + row) * K + k0 + sc * 8, Bs + i * 1024 + l * 16);
    }
    if (AF32) {
      const float* Af = (const float*)Araw;
#pragma unroll
      for (int i4 = 0; i4 < 8; i4++) {
        int i = i4 * 4 + w;
        int row = i * 4 + (l >> 4);
        int g = m0 + row; if (g >= M) g = M - 1;
        int sc = (l & 15) ^ (row & 15);
        gl_lds16(Af + (long)g * K + k0 + sc * 4, As + i * 1024 + l * 16);
      }
    } else {
      const unsigned short* A = (const unsigned short*)Araw;
#pragma unroll
      for (int i4 = 0; i4 < 4; i4++) {
        int i = i4 * 4 + w;
        int row = i * 8 + (l >> 3);
        int g = m0 + row; if (g >= M) g = M - 1;
        int sc = (l & 7) ^ (row & 7);
        gl_lds16(A + (long)g * K + k0 + sc * 8, As + i * 1024 + l * 16);
      }
    }
    __syncthreads();
#pragma unroll
    for (int sk = 0; sk < 2; sk++) {
      bf16x8 af[4], bfr[4];
      if (AF32) {
#pragma unroll
        for (int m = 0; m < 4; m++) {
          int row = wr * 64 + m * 16 + lr;
          int ca = (sk * 8 + lg * 2) ^ (row & 15);
          int cb = (sk * 8 + lg * 2 + 1) ^ (row & 15);
          f32x4 fa = *(const f32x4*)(As + row * 256 + ca * 16);
          f32x4 fb = *(const f32x4*)(As + row * 256 + cb * 16);
          bf16x8 v;
          v[0] = (short)f2bf(fa[0]); v[1] = (short)f2bf(fa[1]);
          v[2] = (short)f2bf(fa[2]); v[3] = (short)f2bf(fa[3]);
          v[4] = (short)f2bf(fb[0]); v[5] = (short)f2bf(fb[1]);
          v[6] = (short)f2bf(fb[2]); v[7] = (short)f2bf(fb[3]);
          af[m] = v;
        }
      } else {
#pragma unroll
        for (int m = 0; m < 4; m++) {
          int row = wr * 64 + m * 16 + lr;
          int c = (sk * 4 + lg) ^ (row & 7);
          af[m] = *(const bf16x8*)(As + row * 128 + c * 16);
        }
      }
#pragma unroll
      for (int n = 0; n < 4; n++) {
        int row = wc * 64 + n * 16 + lr;
        int c = (sk * 4 + lg) ^ (row & 7);
        bfr[n] = *(const bf16x8*)(Bs + row * 128 + c * 16);
      }
#pragma unroll
      for (int m = 0; m < 4; m++)
#pragma unroll
        for (int n = 0; n < 4; n++)
          acc[m][n] = __builtin_amdgcn_mfma_f32_16x16x32_bf16(af[m], bfr[n], acc[m][n], 0, 0, 0);
    }
  }

  float bv[4];
#pragma unroll
  for (int ni = 0; ni < 4; ni++) bv[ni] = bias[n0 + wc * 64 + ni * 16 + lr];
#pragma unroll
  for (int mi = 0; mi < 4; mi++) {
#pragma unroll
    for (int r = 0; r < 4; r++) {
      int row = m0 + wr * 64 + mi * 16 + lg * 4 + r;
      if (row < M) {
#pragma unroll
        for (int ni = 0; ni < 4; ni++) {
          int col = n0 + wc * 64 + ni * 16 + lr;
          float v = acc[mi][ni][r] + bv[ni];
          if (RELU) v = fmaxf(v, 0.f);
          if (OUT_BF16) ((unsigned short*)C)[(long)row * ldc + col] = f2bf(v);
          else          ((float*)C)[(long)row * ldc + col] = v;
        }
      }
    }
  }
}

// ---------------- MFMA flash self-attention (XCD-clustered 1D grid) ----------------
// bid = (pair&7) + 8*((pair>>3)*15 + qtile): all 15 q-tile blocks sharing one
// (b,h) pair's K/V land on ONE XCD (bid%8 const) -> KV fetched once per XCD.
__global__ __launch_bounds__(256) void attn_mfma_kernel(const unsigned short* __restrict__ qkv,
                                                        unsigned short* __restrict__ out) {
  __shared__ unsigned short Vt[32][72];
  __shared__ unsigned short Ps[4][16][72];
  int tid = threadIdx.x;
  int l = tid & 63, w = tid >> 6;
  int lr = l & 15, lg = l >> 4;
  int bid = blockIdx.x;
  int xcd = bid & 7;
  int rest = bid >> 3;          // 0..119
  int pgrp = rest / 15;         // 0..7
  int qt   = rest - pgrp * 15;  // 0..14
  int pair = pgrp * 8 + xcd;    // 0..63
  int q0 = qt * 64;
  int h = pair & 7, b = pair >> 3;
  const float scale = 0.17677669529663687f;

  int qrow = q0 + w * 16 + lr;
  int qclamp = qrow < 899 ? qrow : 899;
  bf16x8 qf = *(const bf16x8*)(qkv + ((long)qclamp * 8 + b) * 768 + h * 32 + lg * 8);

  f32x4 o_acc[2];
  o_acc[0] = (f32x4){0.f, 0.f, 0.f, 0.f};
  o_acc[1] = (f32x4){0.f, 0.f, 0.f, 0.f};
  float m_run[4] = {-1e30f, -1e30f, -1e30f, -1e30f};
  float l_run[4] = {0.f, 0.f, 0.f, 0.f};

  for (int k0 = 0; k0 < NQ; k0 += 64) {
    __syncthreads();
    {
      int key = tid >> 2, dg = tid & 3;
      int kk = k0 + key; if (kk > 899) kk = 899;
      bf16x8 vv = *(const bf16x8*)(qkv + ((long)kk * 8 + b) * 768 + 512 + h * 32 + dg * 8);
#pragma unroll
      for (int j = 0; j < 8; j++) Vt[dg * 8 + j][key] = (unsigned short)vv[j];
    }
    f32x4 sg[4];
#pragma unroll
    for (int ng = 0; ng < 4; ng++) {
      int key = k0 + ng * 16 + lr; int kc = key < 899 ? key : 899;
      bf16x8 kf = *(const bf16x8*)(qkv + ((long)kc * 8 + b) * 768 + 256 + h * 32 + lg * 8);
      sg[ng] = __builtin_amdgcn_mfma_f32_16x16x32_bf16(qf, kf, (f32x4){0.f, 0.f, 0.f, 0.f}, 0, 0, 0);
    }
    float sv[4][4];
#pragma unroll
    for (int ng = 0; ng < 4; ng++) {
      bool bad = (k0 + ng * 16 + lr) >= NQ;
#pragma unroll
      for (int r = 0; r < 4; r++) sv[ng][r] = bad ? -1e30f : sg[ng][r] * scale;
    }
    float p[4][4];
#pragma unroll
    for (int r = 0; r < 4; r++) {
      float rmax = fmaxf(fmaxf(sv[0][r], sv[1][r]), fmaxf(sv[2][r], sv[3][r]));
#pragma unroll
      for (int mk = 8; mk; mk >>= 1) rmax = fmaxf(rmax, __shfl_xor(rmax, mk));
      float mnew = fmaxf(m_run[r], rmax);
      float fs = __expf(m_run[r] - mnew);
      m_run[r] = mnew;
      float ps = 0.f;
#pragma unroll
      for (int ng = 0; ng < 4; ng++) { p[ng][r] = __expf(sv[ng][r] - mnew); ps += p[ng][r]; }
#pragma unroll
      for (int mk = 8; mk; mk >>= 1) ps += __shfl_xor(ps, mk);
      l_run[r] = l_run[r] * fs + ps;
      o_acc[0][r] *= fs;
      o_acc[1][r] *= fs;
    }
#pragma unroll
    for (int ng = 0; ng < 4; ng++)
#pragma unroll
      for (int r = 0; r < 4; r++)
        Ps[w][lg * 4 + r][lr + ng * 16] = f2bf(p[ng][r]);
    __syncthreads();
#pragma unroll
    for (int ks = 0; ks < 2; ks++) {
      bf16x8 pf = *(const bf16x8*)&Ps[w][lr][ks * 32 + lg * 8];
#pragma unroll
      for (int ni = 0; ni < 2; ni++) {
        bf16x8 vf = *(const bf16x8*)&Vt[ni * 16 + lr][ks * 32 + lg * 8];
        o_acc[ni] = __builtin_amdgcn_mfma_f32_16x16x32_bf16(pf, vf, o_acc[ni], 0, 0, 0);
      }
    }
  }
#pragma unroll
  for (int r = 0; r < 4; r++) {
    int orow = q0 + w * 16 + lg * 4 + r;
    if (orow < NQ) {
      float inv = 1.f / l_run[r];
      unsigned short* op = out + ((long)orow * 8 + b) * 256 + h * 32 + lr;
      op[0]  = f2bf(o_acc[0][r] * inv);
      op[16] = f2bf(o_acc[1][r] * inv);
    }
  }
}

// ---------------- bilinear sampler v4: image-clustered blocks, 16 tokens/block ----------------
// bid = img + 8*j (j=0..56): all blocks gathering from V-image `img` share an XCD.
__device__ __forceinline__ void fetch16_acc(const unsigned short* __restrict__ vtmp, int lo, int W,
                                            int yi, int xi, int b, int col0, float wgt,
                                            float* a) {
  if ((xi < 0) | (xi >= W) | (yi < 0) | (yi >= W)) return;
  const unsigned short* p = vtmp + ((long)((lo + yi * W + xi) * BSZ + b)) * 256 + col0;
  bf16x8 r0 = *(const bf16x8*)p;
  bf16x8 r1 = *(const bf16x8*)(p + 8);
#pragma unroll
  for (int j = 0; j < 8; j++) a[j] += wgt * bf2f((unsigned short)r0[j]);
#pragma unroll
  for (int j = 0; j < 8; j++) a[8 + j] += wgt * bf2f((unsigned short)r1[j]);
}

__global__ __launch_bounds__(256) void sampler_kernel(const unsigned short* __restrict__ vtmp,
                                                      const float* __restrict__ oa,
                                                      const float* __restrict__ ref,
                                                      unsigned short* __restrict__ samp) {
  __shared__ float s_off[16][256];
  __shared__ float s_aw[16][128];
  __shared__ float s_ref[16][8];
  int tid = threadIdx.x;
  int bid = blockIdx.x;
  int img = bid & 7;
  int jb  = bid >> 3;            // 0..56
  int qi0 = jb * 16;
#pragma unroll
  for (int k = 0; k < 16; k++) {
    int qi = qi0 + k; if (qi > 899) qi = 899;
    long t = (long)qi * 8 + img;
    s_off[k][tid] = oa[t * 384 + tid];
  }
#pragma unroll
  for (int i = 0; i < 8; i++) {
    int idx = i * 256 + tid;
    int k = idx >> 7, c = idx & 127;
    int qi = qi0 + k; if (qi > 899) qi = 899;
    long t = (long)qi * 8 + img;
    s_aw[k][c] = oa[t * 384 + 256 + c];
  }
  if (tid < 128) {
    int k = tid >> 3;
    int qi = qi0 + k; if (qi > 899) qi = 899;
    long t = (long)qi * 8 + img;
    s_ref[k][tid & 7] = ref[t * 8 + (tid & 7)];
  }
  __syncthreads();
  if (tid < 128) {
    int k = tid >> 3, hh = tid & 7;
    float* p = &s_aw[k][hh * 16];
    float m = -1e30f;
#pragma unroll
    for (int j = 0; j < 16; j++) m = fmaxf(m, p[j]);
    float s = 0.f;
#pragma unroll
    for (int j = 0; j < 16; j++) { p[j] = __expf(p[j] - m); s += p[j]; }
    float inv = 1.f / s;
#pragma unroll
    for (int j = 0; j < 16; j++) p[j] *= inv;
  }
  __syncthreads();
  int w = tid >> 4;
  int l = tid & 15;
  int qi = qi0 + w;
  int h = l >> 1, col0 = h * 32 + (l & 1) * 16;
  int b = img;
  const int Wls[4]  = {100, 50, 25, 13};
  const int lofs[4] = {0, 10000, 12500, 13125};
  float a[16];
#pragma unroll
  for (int j = 0; j < 16; j++) a[j] = 0.f;
#pragma unroll
  for (int lvl = 0; lvl < 4; lvl++) {
    int W = Wls[lvl];
    float Wf = (float)W;
    int lo = lofs[lvl];
    float rx = s_ref[w][lvl * 2 + 0], ry = s_ref[w][lvl * 2 + 1];
#pragma unroll
    for (int p = 0; p < 4; p++) {
      float ox = s_off[w][((h * 4 + lvl) * 4 + p) * 2 + 0];
      float oy = s_off[w][((h * 4 + lvl) * 4 + p) * 2 + 1];
      float x = rx * Wf + ox - 0.5f;
      float y = ry * Wf + oy - 0.5f;
      float x0f = floorf(x), y0f = floorf(y);
      float fx = x - x0f, fy = y - y0f;
      int x0 = (int)x0f, y0 = (int)y0f;
      float aa = s_aw[w][h * 16 + lvl * 4 + p];
      float w00 = aa * (1.f - fx) * (1.f - fy);
      float w01 = aa * fx * (1.f - fy);
      float w10 = aa * (1.f - fx) * fy;
      float w11 = aa * fx * fy;
      fetch16_acc(vtmp, lo, W, y0,     x0,     b, col0, w00, a);
      fetch16_acc(vtmp, lo, W, y0,     x0 + 1, b, col0, w01, a);
      fetch16_acc(vtmp, lo, W, y0 + 1, x0,     b, col0, w10, a);
      fetch16_acc(vtmp, lo, W, y0 + 1, x0 + 1, b, col0, w11, a);
    }
  }
  if (qi < NQ) {
    long t = (long)qi * 8 + img;
    bf16x8 o0, o1;
#pragma unroll
    for (int j = 0; j < 8; j++) { o0[j] = (short)f2bf(a[j]); o1[j] = (short)f2bf(a[8 + j]); }
    *(bf16x8*)(samp + t * 256 + col0) = o0;
    *(bf16x8*)(samp + t * 256 + col0 + 8) = o1;
  }
}

// ---------------- LayerNorm(x + res); optional bf16 out; optional bf16(out+pos) ----------------
__global__ __launch_bounds__(256) void ln_kernel(const float* __restrict__ x,
                                                 const float* __restrict__ res,
                                                 const float* __restrict__ w,
                                                 const float* __restrict__ bvec,
                                                 float* __restrict__ out,
                                                 unsigned short* __restrict__ out_bf,
                                                 const float* __restrict__ pos,
                                                 unsigned short* __restrict__ pos_bf,
                                                 int rows) {
  int wv = threadIdx.x >> 6, lane = threadIdx.x & 63;
  int row = blockIdx.x * 4 + wv;
  if (row >= rows) return;
  float4 xv = *(const float4*)(x + (long)row * 256 + lane * 4);
  float4 rv = *(const float4*)(res + (long)row * 256 + lane * 4);
  float v0 = xv.x + rv.x, v1 = xv.y + rv.y, v2 = xv.z + rv.z, v3 = xv.w + rv.w;
  float s = v0 + v1 + v2 + v3;
#pragma unroll
  for (int o = 32; o; o >>= 1) s += __shfl_xor(s, o);
  float mean = s * (1.f / 256.f);
  float d0 = v0 - mean, d1 = v1 - mean, d2 = v2 - mean, d3 = v3 - mean;
  float q = d0 * d0 + d1 * d1 + d2 * d2 + d3 * d3;
#pragma unroll
  for (int o = 32; o; o >>= 1) q += __shfl_xor(q, o);
  float rstd = rsqrtf(q * (1.f / 256.f) + 1e-5f);
  float4 wv4 = *(const float4*)(w + lane * 4);
  float4 bv4 = *(const float4*)(bvec + lane * 4);
  float o0 = d0 * rstd * wv4.x + bv4.x;
  float o1 = d1 * rstd * wv4.y + bv4.y;
  float o2 = d2 * rstd * wv4.z + bv4.z;
  float o3 = d3 * rstd * wv4.w + bv4.w;
  *(float4*)(out + (long)row * 256 + lane * 4) = make_float4(o0, o1, o2, o3);
  if (out_bf) {
    unsigned short* p = out_bf + (long)row * 256 + lane * 4;
    p[0] = f2bf(o0); p[1] = f2bf(o1); p[2] = f2bf(o2); p[3] = f2bf(o3);
  }
  if (pos_bf) {
    float4 pv = *(const float4*)(pos + (long)row * 256 + lane * 4);
    unsigned short* p = pos_bf + (long)row * 256 + lane * 4;
    p[0] = f2bf(o0 + pv.x); p[1] = f2bf(o1 + pv.y);
    p[2] = f2bf(o2 + pv.z); p[3] = f2bf(o3 + pv.w);
  }
}

extern "C" void kernel_launch(void* const* d_in, const int* in_sizes, int n_in,
                              void* d_out, int out_size, void* d_ws, size_t ws_size,
                              hipStream_t stream) {
  const float* tgt     = (const float*)d_in[0];
  const float* pos     = (const float*)d_in[1];
  const float* refpts  = (const float*)d_in[2];
  const float* memory  = (const float*)d_in[3];
  const float* sa_Wqkv = (const float*)d_in[4];
  const float* sa_bqkv = (const float*)d_in[5];
  const float* sa_Wo   = (const float*)d_in[6];
  const float* sa_bo   = (const float*)d_in[7];
  const float* ln1_w   = (const float*)d_in[8];
  const float* ln1_b   = (const float*)d_in[9];
  const float* ln2_w   = (const float*)d_in[10];
  const float* ln2_b   = (const float*)d_in[11];
  const float* ln3_w   = (const float*)d_in[12];
  const float* ln3_b   = (const float*)d_in[13];
  const float* ca_Woff = (const float*)d_in[14];
  const float* ca_boff = (const float*)d_in[15];
  const float* ca_Wattn= (const float*)d_in[16];
  const float* ca_battn= (const float*)d_in[17];
  const float* ca_Wval = (const float*)d_in[18];
  const float* ca_bval = (const float*)d_in[19];
  const float* ca_Wout = (const float*)d_in[20];
  const float* ca_bout = (const float*)d_in[21];
  const float* ffn_W1  = (const float*)d_in[22];
  const float* ffn_b1  = (const float*)d_in[23];
  const float* ffn_W2  = (const float*)d_in[24];
  const float* ffn_b2  = (const float*)d_in[25];

  char* ws = (char*)d_ws;
  float*          buf_ca = (float*)(ws);
  float*          buf_t3 = (float*)(ws + 8388608);
  unsigned short* t3_bf  = (unsigned short*)(ws + 16777216);
  unsigned short* buf_h  = (unsigned short*)(ws + 20971520);
  float*          buf_f  = (float*)(ws + 36700160);
  float*          bias_cat = (float*)(ws + 44072960);
  unsigned short* buf_v  = (unsigned short*)(ws + 54452224);
  unsigned short* wts    = (unsigned short*)(ws + 112590848);
  unsigned short* buf_q  = (unsigned short*)(ws + 114622464);
  unsigned short* buf_qkv= (unsigned short*)(ws + 118308864);
  float*          buf_oa = (float*)(ws + 118308864);
  unsigned short* buf_o  = (unsigned short*)(ws + 129368064);
  unsigned short* buf_smp= (unsigned short*)(ws + 129368064);
  float*          buf_t2 = (float*)(ws + 133054464);

  const unsigned short* w_qkv = wts + 0;
  const unsigned short* w_o   = wts + 196608;
  const unsigned short* w_val = wts + 262144;
  const unsigned short* w_oa  = wts + 327680;
  const unsigned short* w_out = wts + 425984;
  const unsigned short* w_f1  = wts + 491520;
  const unsigned short* w_f2  = wts + 753664;

  dim3 blk(256);

  // 1. fused prep: weights cast + q=tgt+pos + bias concat
  prep_kernel<<<1398, blk, 0, stream>>>(sa_Wqkv, sa_Wo, ca_Wval, ca_Woff, ca_Wattn,
                                        ca_Wout, ffn_W1, ffn_W2, wts,
                                        tgt, pos, buf_q, ca_boff, ca_battn, bias_cat);

  // 2. batched stage-1 GEMMs: value (1662 blocks) ++ qk (228) ++ v-part (114)
  B3 ops;
  ops.A[0] = memory;   ops.W[0] = w_val;           ops.bias[0] = ca_bval;      ops.C[0] = buf_v;
  ops.M[0] = MVAL;     ops.ldc[0] = 256;           ops.af32[0] = 1;            ops.nx[0] = 2;
  ops.A[1] = buf_q;    ops.W[1] = w_qkv;           ops.bias[1] = sa_bqkv;      ops.C[1] = buf_qkv;
  ops.M[1] = NTOK;     ops.ldc[1] = 768;           ops.af32[1] = 0;            ops.nx[1] = 4;
  ops.A[2] = tgt;      ops.W[2] = w_qkv + 512*256; ops.bias[2] = sa_bqkv + 512; ops.C[2] = buf_qkv + 512;
  ops.M[2] = NTOK;     ops.ldc[2] = 768;           ops.af32[2] = 1;            ops.nx[2] = 2;
  ops.blk0[0] = 0; ops.blk0[1] = 1662; ops.blk0[2] = 1890;
  gemm_batch3_kernel<<<2004, blk, 0, stream>>>(ops);

  // 3. flash self-attention (XCD-clustered 1D grid: 8 XCD x 8 pair-groups x 15 q-tiles)
  attn_mfma_kernel<<<960, blk, 0, stream>>>(buf_qkv, buf_o);
  // 4. o @ Wo^T (f32 out) -> buf_t2
  gemm_s_kernel<0, 0, 0, 4><<<dim3(2, 57), blk, 0, stream>>>(buf_o, w_o, sa_bo,
                                                             buf_t2, NTOK, 256);
  // 5. t2 = LN2(g6 + tgt) in place; also q2_bf = bf16(t2 + pos)
  ln_kernel<<<1800, blk, 0, stream>>>(buf_t2, tgt, ln2_w, ln2_b, buf_t2, nullptr,
                                      pos, buf_q, NTOK);
  // 6. offsets + attention logits fused: [7200,384] (f32, ldc 384)
  gemm_s_kernel<0, 0, 0, 4><<<dim3(3, 57), blk, 0, stream>>>(buf_q, w_oa, bias_cat,
                                                             buf_oa, NTOK, 384);
  // 7. bilinear sampling (image-clustered; softmax fused; bf16 out)
  sampler_kernel<<<456, blk, 0, stream>>>(buf_v, buf_oa, refpts, buf_smp);
  // 8. ca = samp @ Wout^T (f32)
  gemm_s_kernel<0, 0, 0, 4><<<dim3(2, 57), blk, 0, stream>>>(buf_smp, w_out, ca_bout,
                                                             buf_ca, NTOK, 256);
  // 9. t3 = LN1(ca + t2), f32 + bf16
  ln_kernel<<<1800, blk, 0, stream>>>(buf_ca, buf_t2, ln1_w, ln1_b, buf_t3, t3_bf,
                                      nullptr, nullptr, NTOK);
  // 10. h = relu(t3 @ W1^T) (bf16)
  gemm_s_kernel<0, 1, 1, 4><<<dim3(8, 57), blk, 0, stream>>>(t3_bf, w_f1, ffn_b1,
                                                             buf_h, NTOK, 1024);
  // 11. f = h @ W2^T (f32), K=1024
  gemm_s_kernel<0, 0, 0, 16><<<dim3(2, 57), blk, 0, stream>>>(buf_h, w_f2, ffn_b2,
                                                              buf_f, NTOK, 256);
  // 12. out = LN3(f + t3)
  ln_kernel<<<1800, blk, 0, stream>>>(buf_f, buf_t3, ln3_w, ln3_b, (float*)d_out, nullptr,
                                      nullptr, nullptr, NTOK);
}